// Round 11
// baseline (114.179 us; speedup 1.0000x reference)
//
#include <hip/hip_runtime.h>
#include <hip/hip_bf16.h>

#define B_ 8
#define D_ 128
#define NH 8
#define L_ 1024
#define DK 16

typedef __attribute__((ext_vector_type(4))) short s4;
typedef __attribute__((ext_vector_type(4))) float f4;

static __device__ __forceinline__ unsigned short f2bf(float f) {
    __hip_bfloat16 h = __float2bfloat16(f);
    return *reinterpret_cast<unsigned short*>(&h);
}
static __device__ __forceinline__ unsigned pack2(float a, float b) {
    return (unsigned)f2bf(a) | ((unsigned)f2bf(b) << 16);
}
static __device__ __forceinline__ s4 pack4(float a, float b, float c, float d) {
    union { unsigned u[2]; s4 v; } un;
    un.u[0] = pack2(a, b);
    un.u[1] = pack2(c, d);
    return un.v;
}

// 16x16x16 bf16 MFMA: D = A*B + C.  A[m=lane&15][k=(lane>>4)*4+jj],
// B[k=(lane>>4)*4+jj][n=lane&15], C/D[row=(lane>>4)*4+reg][col=lane&15].
// (A/B/C mapping HW-verified in rounds 4-8,10 end-to-end.)
// R9 lesson: 512-THREAD blocks caused post-timing divergence under graph
// replay; keep blocks at 256 threads and scale via grid size instead.
#if __has_builtin(__builtin_amdgcn_mfma_f32_16x16x16_bf16)
#define MFMA16(a, b, c) __builtin_amdgcn_mfma_f32_16x16x16_bf16(a, b, c, 0, 0, 0)
#elif __has_builtin(__builtin_amdgcn_mfma_f32_16x16x16bf16_1k)
#define MFMA16(a, b, c) __builtin_amdgcn_mfma_f32_16x16x16bf16_1k(a, b, c, 0, 0, 0)
#else
static __device__ __forceinline__ f4 mfma16_asm(s4 a, s4 b, f4 c) {
    f4 d;
    asm volatile("v_mfma_f32_16x16x16_bf16 %0, %1, %2, %3"
                 : "=&v"(d) : "v"(a), "v"(b), "v"(c));
    return d;
}
#define MFMA16(a, b, c) mfma16_asm(a, b, c)
#endif

// ---------------------------------------------------------------------------
// Kernel 1: MFMA QKV projection (unchanged from R7/R10 — full-harness-verified).
//   Qt[bh][l][k]  (packed b64)       which==0
//   Kt[bh][j][k]  *0.25, packed b64  which==1
//   Vt[bh][v][i]  (short stores)     which==2
// grid (8, 64, 3), block 256.  1536 blocks -> ~6 blocks/CU.
// ---------------------------------------------------------------------------
__global__ __launch_bounds__(256)
void proj_kernel(const float* __restrict__ x,
                 const float* __restrict__ Wq,
                 const float* __restrict__ Wk,
                 const float* __restrict__ Wv,
                 unsigned short* __restrict__ Qt,
                 unsigned short* __restrict__ Kt,
                 unsigned short* __restrict__ Vt) {
    const int lane = threadIdx.x & 63;
    const int wv   = threadIdx.x >> 6;
    const int m = lane & 15, q = lane >> 4;
    const int bh = blockIdx.y, b = bh >> 3, h = bh & 7;
    const int which = blockIdx.z;
    const int n0 = (blockIdx.x * 4 + wv) * 32;

    const float* W = (which == 0) ? Wq : (which == 1) ? Wk : Wv;
    const float* Wrow = W + ((size_t)((h * B_ + b) * DK + m)) * D_;  // A row m
    const float* xb = x + (size_t)b * D_ * L_ + n0 + m;

    f4 acc0 = {0.f, 0.f, 0.f, 0.f}, acc1 = {0.f, 0.f, 0.f, 0.f};
#pragma unroll
    for (int kb = 0; kb < 8; ++kb) {
        const int k4 = kb * 16 + q * 4;
        float4 wf = *(const float4*)(Wrow + k4);
        s4 a = pack4(wf.x, wf.y, wf.z, wf.w);

        const float* xc = xb + (size_t)k4 * L_;
        float b00 = xc[0];           float b01 = xc[L_];
        float b02 = xc[2 * L_];      float b03 = xc[3 * L_];
        float b10 = xc[16];          float b11 = xc[L_ + 16];
        float b12 = xc[2 * L_ + 16]; float b13 = xc[3 * L_ + 16];
        s4 bf0 = pack4(b00, b01, b02, b03);
        s4 bf1 = pack4(b10, b11, b12, b13);

        acc0 = MFMA16(a, bf0, acc0);
        acc1 = MFMA16(a, bf1, acc1);
    }

    if (which == 2) {
        unsigned short* vp = Vt + ((size_t)bh * DK + q * 4) * L_ + n0 + m;
        vp[0]      = f2bf(acc0[0]); vp[L_]     = f2bf(acc0[1]);
        vp[2 * L_] = f2bf(acc0[2]); vp[3 * L_] = f2bf(acc0[3]);
        vp += 16;
        vp[0]      = f2bf(acc1[0]); vp[L_]     = f2bf(acc1[1]);
        vp[2 * L_] = f2bf(acc1[2]); vp[3 * L_] = f2bf(acc1[3]);
    } else {
        const float sc = (which == 1) ? 0.25f : 1.0f;
        unsigned short* T = (which == 0) ? Qt : Kt;
        uint2 u0, u1;
        u0.x = pack2(acc0[0] * sc, acc0[1] * sc);
        u0.y = pack2(acc0[2] * sc, acc0[3] * sc);
        u1.x = pack2(acc1[0] * sc, acc1[1] * sc);
        u1.y = pack2(acc1[2] * sc, acc1[3] * sc);
        *(uint2*)(T + ((size_t)bh * L_ + n0 + m) * DK + q * 4)      = u0;
        *(uint2*)(T + ((size_t)bh * L_ + n0 + 16 + m) * DK + q * 4) = u1;
    }
}

// ---------------------------------------------------------------------------
// Kernel 2: FUSED attention + output projection.  R10 ran 256 blocks
// (1 block/CU = 1 wave/SIMD, zero latency hiding).  Now: one block per
// (b, 16 cols) -> 512 blocks = 2 blocks/CU = 2 waves/SIMD; per-wave work
// halves (2 heads x 1 j-tile instead of 2x2).  Block stays 256 threads.
// Phase 1: wave wv handles heads {wv, wv+4}, j-tile jblk; normalized head
//   tile -> LDS hls[l_local 0..15][d] bf16.
// Phase 2: wave wv computes o-chunks {2wv, 2wv+1}: out = Wo @ hls.
// grid (64, 8), block 256.
// ---------------------------------------------------------------------------
__global__ __launch_bounds__(256)
void attn_out_kernel(const unsigned short* __restrict__ Qt,
                     const unsigned short* __restrict__ Kt,
                     const unsigned short* __restrict__ Vt,
                     const float* __restrict__ Wo,
                     float* __restrict__ out) {
    const int lane = threadIdx.x & 63;
    const int wv   = threadIdx.x >> 6;        // 0..3
    const int m = lane & 15, q = lane >> 4;
    const int b    = blockIdx.y;
    const int jblk = blockIdx.x * 16;

    __shared__ unsigned short hls[16][132];   // [l_local][d], 4.1 KB

    // ---- Phase 1: heads wv and wv+4, columns jblk..jblk+15
#pragma unroll
    for (int hh = 0; hh < 2; ++hh) {
        const int h  = wv + hh * 4;
        const int bh = b * NH + h;

        s4 bk = *(const s4*)(Kt + ((size_t)bh * L_ + jblk + m) * DK + q * 4);

        f4 O = {0.f, 0.f, 0.f, 0.f};
        float ls = 0.f;
        const unsigned short* qbase = Qt + (size_t)bh * L_ * DK + q * 4;
        const unsigned short* vbase = Vt + ((size_t)bh * DK + m) * L_ + q * 4;

#pragma unroll 4
        for (int i0 = 0; i0 < L_; i0 += 16) {
            s4 aq = *(const s4*)(qbase + (size_t)(i0 + m) * DK);
            s4 av = *(const s4*)(vbase + i0);

            f4 z = {0.f, 0.f, 0.f, 0.f};
            f4 S = MFMA16(aq, bk, z);        // S[i0+q*4+r][jblk+m]

            float p0 = __expf(S[0]), p1 = __expf(S[1]);
            float p2 = __expf(S[2]), p3 = __expf(S[3]);
            ls += (p0 + p1) + (p2 + p3);

            s4 pb;
            pb[0] = (short)f2bf(p0); pb[1] = (short)f2bf(p1);
            pb[2] = (short)f2bf(p2); pb[3] = (short)f2bf(p3);

            O = MFMA16(av, pb, O);           // O[v=q*4+r][col] += V*P
        }

        ls += __shfl_xor(ls, 16, 64);
        ls += __shfl_xor(ls, 32, 64);
        const float inv = 1.f / ls;

        // head tile row l_local = m, cols d = h*16 + q*4 + r
        uint2 o;
        o.x = pack2(O[0] * inv, O[1] * inv);
        o.y = pack2(O[2] * inv, O[3] * inv);
        *(uint2*)&hls[m][h * 16 + q * 4] = o;
    }

    __syncthreads();

    // ---- Phase 2: o-chunks {2wv, 2wv+1} -> out[b][o0+q*4+r][jblk+m]
#pragma unroll
    for (int t = 0; t < 2; ++t) {
        const int o0 = (wv * 2 + t) * 16;
        const float* Wrow = Wo + ((size_t)b * D_ + o0 + m) * D_;

        f4 acc = {0.f, 0.f, 0.f, 0.f};
#pragma unroll
        for (int kb = 0; kb < 8; ++kb) {
            const int k4 = kb * 16 + q * 4;
            float4 wf = *(const float4*)(Wrow + k4);
            s4 a  = pack4(wf.x, wf.y, wf.z, wf.w);
            s4 b0 = *(const s4*)&hls[m][k4];        // B[k][n=l] = hls[l][k]
            acc = MFMA16(a, b0, acc);
        }

        float* op = out + ((size_t)b * D_ + o0 + q * 4) * L_ + jblk + m;
        op[0]      = acc[0]; op[L_]     = acc[1];
        op[2 * L_] = acc[2]; op[3 * L_] = acc[3];
    }
}

// ---------------------------------------------------------------------------
extern "C" void kernel_launch(void* const* d_in, const int* in_sizes, int n_in,
                              void* d_out, int out_size, void* d_ws, size_t ws_size,
                              hipStream_t stream) {
    const float* x  = (const float*)d_in[0];
    const float* Wq = (const float*)d_in[1];
    const float* Wk = (const float*)d_in[2];
    const float* Wv = (const float*)d_in[3];
    const float* Wo = (const float*)d_in[4];
    float* out = (float*)d_out;

    const size_t SEG = (size_t)B_ * NH * DK * L_;   // 1,048,576 elements
    unsigned short* Qt = (unsigned short*)d_ws;     // bf16 [bh][l][k], 2 MB
    unsigned short* Kt = Qt + SEG;                  // bf16 [bh][j][k], 2 MB
    unsigned short* Vt = Kt + SEG;                  // bf16 [bh][v][i], 2 MB

    proj_kernel<<<dim3(8, B_ * NH, 3), 256, 0, stream>>>(x, Wq, Wk, Wv, Qt, Kt, Vt);
    attn_out_kernel<<<dim3(64, B_), 256, 0, stream>>>(Qt, Kt, Vt, Wo, out);
}

// Round 12
// 110.292 us; speedup vs baseline: 1.0352x; 1.0352x over previous
//
#include <hip/hip_runtime.h>
#include <hip/hip_bf16.h>

#define B_ 8
#define D_ 128
#define NH 8
#define L_ 1024
#define DK 16

typedef __attribute__((ext_vector_type(4))) short s4;
typedef __attribute__((ext_vector_type(4))) float f4;

static __device__ __forceinline__ unsigned short f2bf(float f) {
    __hip_bfloat16 h = __float2bfloat16(f);
    return *reinterpret_cast<unsigned short*>(&h);
}
static __device__ __forceinline__ unsigned pack2(float a, float b) {
    return (unsigned)f2bf(a) | ((unsigned)f2bf(b) << 16);
}
static __device__ __forceinline__ s4 pack4(float a, float b, float c, float d) {
    union { unsigned u[2]; s4 v; } un;
    un.u[0] = pack2(a, b);
    un.u[1] = pack2(c, d);
    return un.v;
}

// 16x16x16 bf16 MFMA: D = A*B + C.  A[m=lane&15][k=(lane>>4)*4+jj],
// B[k=(lane>>4)*4+jj][n=lane&15], C/D[row=(lane>>4)*4+reg][col=lane&15].
// (HW-verified rounds 4-11.)
// R9 lesson: 512-THREAD blocks broke post-timing replay; stay at 256.
// R11 lesson: attn_out is latency-chain-bound — per-wave ILP (independent
// MFMA chains) beats wave count; 512-block/1-jtile variant regressed.
#if __has_builtin(__builtin_amdgcn_mfma_f32_16x16x16_bf16)
#define MFMA16(a, b, c) __builtin_amdgcn_mfma_f32_16x16x16_bf16(a, b, c, 0, 0, 0)
#elif __has_builtin(__builtin_amdgcn_mfma_f32_16x16x16bf16_1k)
#define MFMA16(a, b, c) __builtin_amdgcn_mfma_f32_16x16x16bf16_1k(a, b, c, 0, 0, 0)
#else
static __device__ __forceinline__ f4 mfma16_asm(s4 a, s4 b, f4 c) {
    f4 d;
    asm volatile("v_mfma_f32_16x16x16_bf16 %0, %1, %2, %3"
                 : "=&v"(d) : "v"(a), "v"(b), "v"(c));
    return d;
}
#define MFMA16(a, b, c) mfma16_asm(a, b, c)
#endif

// ---------------------------------------------------------------------------
// Kernel 1: MFMA QKV projection (unchanged — full-harness-verified R7/R10).
//   Qt[bh][l][k]  (packed b64)       which==0
//   Kt[bh][j][k]  *0.25, packed b64  which==1
//   Vt[bh][v][i]  (short stores)     which==2
// grid (8, 64, 3), block 256.  1536 blocks -> ~6 blocks/CU.
// ---------------------------------------------------------------------------
__global__ __launch_bounds__(256)
void proj_kernel(const float* __restrict__ x,
                 const float* __restrict__ Wq,
                 const float* __restrict__ Wk,
                 const float* __restrict__ Wv,
                 unsigned short* __restrict__ Qt,
                 unsigned short* __restrict__ Kt,
                 unsigned short* __restrict__ Vt) {
    const int lane = threadIdx.x & 63;
    const int wv   = threadIdx.x >> 6;
    const int m = lane & 15, q = lane >> 4;
    const int bh = blockIdx.y, b = bh >> 3, h = bh & 7;
    const int which = blockIdx.z;
    const int n0 = (blockIdx.x * 4 + wv) * 32;

    const float* W = (which == 0) ? Wq : (which == 1) ? Wk : Wv;
    const float* Wrow = W + ((size_t)((h * B_ + b) * DK + m)) * D_;  // A row m
    const float* xb = x + (size_t)b * D_ * L_ + n0 + m;

    f4 acc0 = {0.f, 0.f, 0.f, 0.f}, acc1 = {0.f, 0.f, 0.f, 0.f};
#pragma unroll
    for (int kb = 0; kb < 8; ++kb) {
        const int k4 = kb * 16 + q * 4;
        float4 wf = *(const float4*)(Wrow + k4);
        s4 a = pack4(wf.x, wf.y, wf.z, wf.w);

        const float* xc = xb + (size_t)k4 * L_;
        float b00 = xc[0];           float b01 = xc[L_];
        float b02 = xc[2 * L_];      float b03 = xc[3 * L_];
        float b10 = xc[16];          float b11 = xc[L_ + 16];
        float b12 = xc[2 * L_ + 16]; float b13 = xc[3 * L_ + 16];
        s4 bf0 = pack4(b00, b01, b02, b03);
        s4 bf1 = pack4(b10, b11, b12, b13);

        acc0 = MFMA16(a, bf0, acc0);
        acc1 = MFMA16(a, bf1, acc1);
    }

    if (which == 2) {
        unsigned short* vp = Vt + ((size_t)bh * DK + q * 4) * L_ + n0 + m;
        vp[0]      = f2bf(acc0[0]); vp[L_]     = f2bf(acc0[1]);
        vp[2 * L_] = f2bf(acc0[2]); vp[3 * L_] = f2bf(acc0[3]);
        vp += 16;
        vp[0]      = f2bf(acc1[0]); vp[L_]     = f2bf(acc1[1]);
        vp[2 * L_] = f2bf(acc1[2]); vp[3 * L_] = f2bf(acc1[3]);
    } else {
        const float sc = (which == 1) ? 0.25f : 1.0f;
        unsigned short* T = (which == 0) ? Qt : Kt;
        uint2 u0, u1;
        u0.x = pack2(acc0[0] * sc, acc0[1] * sc);
        u0.y = pack2(acc0[2] * sc, acc0[3] * sc);
        u1.x = pack2(acc1[0] * sc, acc1[1] * sc);
        u1.y = pack2(acc1[2] * sc, acc1[3] * sc);
        *(uint2*)(T + ((size_t)bh * L_ + n0 + m) * DK + q * 4)      = u0;
        *(uint2*)(T + ((size_t)bh * L_ + n0 + 16 + m) * DK + q * 4) = u1;
    }
}

// ---------------------------------------------------------------------------
// Kernel 2: FUSED attention + output projection.  R7 grid/block shape
// (grid (32,8), block 256 — harness-verified), but phase 1 now interleaves
// BOTH heads' i-loops: per iteration 4 independent S-MFMA chains
// (2 heads x 2 j-tiles), 16 exps, 4 O-MFMAs — doubling chain-level ILP
// vs R7's sequential hh loop.  Math order per head unchanged.
// ---------------------------------------------------------------------------
__global__ __launch_bounds__(256)
void attn_out_kernel(const unsigned short* __restrict__ Qt,
                     const unsigned short* __restrict__ Kt,
                     const unsigned short* __restrict__ Vt,
                     const float* __restrict__ Wo,
                     float* __restrict__ out) {
    const int lane = threadIdx.x & 63;
    const int wv   = threadIdx.x >> 6;
    const int m = lane & 15, q = lane >> 4;
    const int b    = blockIdx.y;
    const int jblk = blockIdx.x * 32;

    __shared__ unsigned short hls[32][132];   // [l_local][d], 8.25 KB

    const int h0  = wv,      bh0 = b * NH + h0;
    const int h1  = wv + 4,  bh1 = b * NH + h1;

    s4 bk00 = *(const s4*)(Kt + ((size_t)bh0 * L_ + jblk + m) * DK + q * 4);
    s4 bk01 = *(const s4*)(Kt + ((size_t)bh0 * L_ + jblk + 16 + m) * DK + q * 4);
    s4 bk10 = *(const s4*)(Kt + ((size_t)bh1 * L_ + jblk + m) * DK + q * 4);
    s4 bk11 = *(const s4*)(Kt + ((size_t)bh1 * L_ + jblk + 16 + m) * DK + q * 4);

    f4 O00 = {0.f,0.f,0.f,0.f}, O01 = {0.f,0.f,0.f,0.f};
    f4 O10 = {0.f,0.f,0.f,0.f}, O11 = {0.f,0.f,0.f,0.f};
    float ls00 = 0.f, ls01 = 0.f, ls10 = 0.f, ls11 = 0.f;

    const unsigned short* qb0 = Qt + (size_t)bh0 * L_ * DK + q * 4;
    const unsigned short* vb0 = Vt + ((size_t)bh0 * DK + m) * L_ + q * 4;
    const unsigned short* qb1 = Qt + (size_t)bh1 * L_ * DK + q * 4;
    const unsigned short* vb1 = Vt + ((size_t)bh1 * DK + m) * L_ + q * 4;

#pragma unroll 2
    for (int i0 = 0; i0 < L_; i0 += 16) {
        s4 aq0 = *(const s4*)(qb0 + (size_t)(i0 + m) * DK);
        s4 av0 = *(const s4*)(vb0 + i0);
        s4 aq1 = *(const s4*)(qb1 + (size_t)(i0 + m) * DK);
        s4 av1 = *(const s4*)(vb1 + i0);

        f4 z = {0.f, 0.f, 0.f, 0.f};
        f4 S00 = MFMA16(aq0, bk00, z);   // 4 independent S chains
        f4 S01 = MFMA16(aq0, bk01, z);
        f4 S10 = MFMA16(aq1, bk10, z);
        f4 S11 = MFMA16(aq1, bk11, z);

        float p000 = __expf(S00[0]), p001 = __expf(S00[1]);
        float p002 = __expf(S00[2]), p003 = __expf(S00[3]);
        float p010 = __expf(S01[0]), p011 = __expf(S01[1]);
        float p012 = __expf(S01[2]), p013 = __expf(S01[3]);
        float p100 = __expf(S10[0]), p101 = __expf(S10[1]);
        float p102 = __expf(S10[2]), p103 = __expf(S10[3]);
        float p110 = __expf(S11[0]), p111 = __expf(S11[1]);
        float p112 = __expf(S11[2]), p113 = __expf(S11[3]);

        ls00 += (p000 + p001) + (p002 + p003);
        ls01 += (p010 + p011) + (p012 + p013);
        ls10 += (p100 + p101) + (p102 + p103);
        ls11 += (p110 + p111) + (p112 + p113);

        s4 pb00, pb01, pb10, pb11;
        pb00[0] = (short)f2bf(p000); pb00[1] = (short)f2bf(p001);
        pb00[2] = (short)f2bf(p002); pb00[3] = (short)f2bf(p003);
        pb01[0] = (short)f2bf(p010); pb01[1] = (short)f2bf(p011);
        pb01[2] = (short)f2bf(p012); pb01[3] = (short)f2bf(p013);
        pb10[0] = (short)f2bf(p100); pb10[1] = (short)f2bf(p101);
        pb10[2] = (short)f2bf(p102); pb10[3] = (short)f2bf(p103);
        pb11[0] = (short)f2bf(p110); pb11[1] = (short)f2bf(p111);
        pb11[2] = (short)f2bf(p112); pb11[3] = (short)f2bf(p113);

        O00 = MFMA16(av0, pb00, O00);    // 4 independent O chains
        O01 = MFMA16(av0, pb01, O01);
        O10 = MFMA16(av1, pb10, O10);
        O11 = MFMA16(av1, pb11, O11);
    }

    ls00 += __shfl_xor(ls00, 16, 64); ls00 += __shfl_xor(ls00, 32, 64);
    ls01 += __shfl_xor(ls01, 16, 64); ls01 += __shfl_xor(ls01, 32, 64);
    ls10 += __shfl_xor(ls10, 16, 64); ls10 += __shfl_xor(ls10, 32, 64);
    ls11 += __shfl_xor(ls11, 16, 64); ls11 += __shfl_xor(ls11, 32, 64);
    const float i00 = 1.f / ls00, i01 = 1.f / ls01;
    const float i10 = 1.f / ls10, i11 = 1.f / ls11;

    // head tile rows l_local = {m, 16+m}, cols d = h*16 + q*4 + r
    uint2 o;
    o.x = pack2(O00[0] * i00, O00[1] * i00);
    o.y = pack2(O00[2] * i00, O00[3] * i00);
    *(uint2*)&hls[m][h0 * 16 + q * 4] = o;
    o.x = pack2(O01[0] * i01, O01[1] * i01);
    o.y = pack2(O01[2] * i01, O01[3] * i01);
    *(uint2*)&hls[16 + m][h0 * 16 + q * 4] = o;
    o.x = pack2(O10[0] * i10, O10[1] * i10);
    o.y = pack2(O10[2] * i10, O10[3] * i10);
    *(uint2*)&hls[m][h1 * 16 + q * 4] = o;
    o.x = pack2(O11[0] * i11, O11[1] * i11);
    o.y = pack2(O11[2] * i11, O11[3] * i11);
    *(uint2*)&hls[16 + m][h1 * 16 + q * 4] = o;

    __syncthreads();

    // ---- Phase 2: out[b][o0+q*4+r][jblk(+16)+m], 2 o-chunks per wave
#pragma unroll
    for (int t = 0; t < 2; ++t) {
        const int oc = wv * 2 + t;
        const int o0 = oc * 16;
        const float* Wrow = Wo + ((size_t)b * D_ + o0 + m) * D_;

        f4 acc0 = {0.f, 0.f, 0.f, 0.f}, acc1 = {0.f, 0.f, 0.f, 0.f};
#pragma unroll
        for (int kb = 0; kb < 8; ++kb) {
            const int k4 = kb * 16 + q * 4;
            float4 wf = *(const float4*)(Wrow + k4);
            s4 a  = pack4(wf.x, wf.y, wf.z, wf.w);
            s4 b0 = *(const s4*)&hls[m][k4];        // B[k][n=l] = hls[l][k]
            s4 b1 = *(const s4*)&hls[16 + m][k4];
            acc0 = MFMA16(a, b0, acc0);
            acc1 = MFMA16(a, b1, acc1);
        }

        float* op = out + ((size_t)b * D_ + o0 + q * 4) * L_ + jblk + m;
        op[0]      = acc0[0]; op[L_]     = acc0[1];
        op[2 * L_] = acc0[2]; op[3 * L_] = acc0[3];
        op += 16;
        op[0]      = acc1[0]; op[L_]     = acc1[1];
        op[2 * L_] = acc1[2]; op[3 * L_] = acc1[3];
    }
}

// ---------------------------------------------------------------------------
extern "C" void kernel_launch(void* const* d_in, const int* in_sizes, int n_in,
                              void* d_out, int out_size, void* d_ws, size_t ws_size,
                              hipStream_t stream) {
    const float* x  = (const float*)d_in[0];
    const float* Wq = (const float*)d_in[1];
    const float* Wk = (const float*)d_in[2];
    const float* Wv = (const float*)d_in[3];
    const float* Wo = (const float*)d_in[4];
    float* out = (float*)d_out;

    const size_t SEG = (size_t)B_ * NH * DK * L_;   // 1,048,576 elements
    unsigned short* Qt = (unsigned short*)d_ws;     // bf16 [bh][l][k], 2 MB
    unsigned short* Kt = Qt + SEG;                  // bf16 [bh][j][k], 2 MB
    unsigned short* Vt = Kt + SEG;                  // bf16 [bh][v][i], 2 MB

    proj_kernel<<<dim3(8, B_ * NH, 3), 256, 0, stream>>>(x, Wq, Wk, Wv, Qt, Kt, Vt);
    attn_out_kernel<<<dim3(32, B_), 256, 0, stream>>>(Qt, Kt, Vt, Wo, out);
}